// Round 4
// baseline (91.221 us; speedup 1.0000x reference)
//
#include <hip/hip_runtime.h>

#define BATCH 8
#define NDIM 2048
#define FDIM 256
#define CH 32   // row-chunks for column-sum partials (64 rows each)

typedef float f32x4 __attribute__((ext_vector_type(4)));
typedef short bf16x8 __attribute__((ext_vector_type(8)));
typedef short bf16x4 __attribute__((ext_vector_type(4)));

__device__ __forceinline__ short f2bf(float f) {
  union { float f; unsigned u; } v{f};
  return (short)((v.u + 0x7FFFu + ((v.u >> 16) & 1u)) >> 16);  // RNE
}

__device__ __forceinline__ void gload_lds16(const void* g, void* l) {
  __builtin_amdgcn_global_load_lds(
      (const __attribute__((address_space(1))) void*)g,
      (__attribute__((address_space(3))) void*)l, 16, 0, 0);
}

// ---- Kernel 1: partial column sums of adj ----
// grid = BATCH * CH * 2 colblocks, block = 256.  part[b][ch][col]
__global__ __launch_bounds__(256) void k_colsum(const float* __restrict__ adj,
                                                float* __restrict__ part) {
  int bid = blockIdx.x;
  int cb = bid & 1;
  int ch = (bid >> 1) & (CH - 1);
  int b = bid >> 6;
  int col = cb * 1024 + threadIdx.x * 4;
  const float* p = adj + (size_t)b * NDIM * NDIM + (size_t)(ch * 64) * NDIM + col;
  f32x4 acc = {0.f, 0.f, 0.f, 0.f};
#pragma unroll 8
  for (int i = 0; i < 64; ++i) acc += *(const f32x4*)(p + (size_t)i * NDIM);
  *(f32x4*)(part + (size_t)(b * CH + ch) * NDIM + col) = acc;
}

// ---- Kernel 2 (merged): blocks 0..63 -> d = rsqrt(colsum); 64..79 -> Wt ----
__global__ __launch_bounds__(256) void k_small(const float* __restrict__ part,
                                               float* __restrict__ dnorm,
                                               const float* __restrict__ w,
                                               short* __restrict__ wt) {
  int t = threadIdx.x;
  if (blockIdx.x < 64) {
    int idx = blockIdx.x * 256 + t;  // b*NDIM + j
    int b = idx >> 11, j = idx & (NDIM - 1);
    float s = 0.f;
#pragma unroll
    for (int c = 0; c < CH; ++c) s += part[(size_t)(b * CH + c) * NDIM + j];
    dnorm[idx] = rsqrtf(s);
  } else {
    __shared__ float tile[64][65];
    int bb = blockIdx.x - 64;
    int bx = bb & 3, by = bb >> 2;
    int f0 = by * 64, o0 = bx * 64;
    int c4 = 4 * (t & 15);
#pragma unroll
    for (int q = 0; q < 4; ++q) {
      int r = (t >> 4) + 16 * q;
      f32x4 v = *(const f32x4*)(w + (size_t)(f0 + r) * FDIM + o0 + c4);
#pragma unroll
      for (int i = 0; i < 4; ++i) tile[r][c4 + i] = v[i];
    }
    __syncthreads();
#pragma unroll
    for (int q = 0; q < 4; ++q) {
      int r = (t >> 4) + 16 * q;
      bf16x4 pk;
#pragma unroll
      for (int i = 0; i < 4; ++i) pk[i] = f2bf(tile[c4 + i][r]);
      *(bf16x4*)(wt + (size_t)(o0 + r) * FDIM + f0 + c4) = pk;
    }
  }
}

// ---- Kernel 3: St[b][o][m] = bf16(d[b][m] * (X @ W)[m][o]) ----
__global__ __launch_bounds__(256) void k_support(const float* __restrict__ in,
                                                 const short* __restrict__ wt,
                                                 const float* __restrict__ dnorm,
                                                 short* __restrict__ st) {
  __shared__ short Al[64 * 32];
  __shared__ short Bl[256 * 32];
  int t = threadIdx.x, lane = t & 63, w = t >> 6;
  int b = blockIdx.x >> 5;
  int m0 = (blockIdx.x & 31) * 64;
  const float* inb = in + ((size_t)b * NDIM + m0) * FDIM;

  f32x4 acc[4][4];
#pragma unroll
  for (int m = 0; m < 4; ++m)
#pragma unroll
    for (int n = 0; n < 4; ++n) acc[m][n] = {0.f, 0.f, 0.f, 0.f};

  int ar = t >> 2, ac = t & 3;
  for (int it = 0; it < 8; ++it) {
    int k0 = it * 32;
    {
      f32x4 v0 = *(const f32x4*)(inb + (size_t)ar * FDIM + k0 + 8 * ac);
      f32x4 v1 = *(const f32x4*)(inb + (size_t)ar * FDIM + k0 + 8 * ac + 4);
      bf16x8 p;
#pragma unroll
      for (int i = 0; i < 4; ++i) { p[i] = f2bf(v0[i]); p[4 + i] = f2bf(v1[i]); }
      *(bf16x8*)&Al[ar * 32 + 8 * ac] = p;
    }
#pragma unroll
    for (int i = 0; i < 4; ++i) {
      int ss = i * 256 + t;
      int o = ss >> 2, c = ss & 3;
      gload_lds16(wt + (size_t)o * FDIM + k0 + 8 * c, &Bl[ss * 8]);
    }
    __syncthreads();
    bf16x8 af[4], bf[4];
#pragma unroll
    for (int m = 0; m < 4; ++m)
      af[m] = *(const bf16x8*)&Al[(16 * m + (lane & 15)) * 32 + (lane >> 4) * 8];
#pragma unroll
    for (int n = 0; n < 4; ++n)
      bf[n] = *(const bf16x8*)&Bl[(64 * w + 16 * n + (lane & 15)) * 32 + (lane >> 4) * 8];
#pragma unroll
    for (int m = 0; m < 4; ++m)
#pragma unroll
      for (int n = 0; n < 4; ++n)
        acc[m][n] = __builtin_amdgcn_mfma_f32_16x16x32_bf16(af[m], bf[n], acc[m][n], 0, 0, 0);
    __syncthreads();
  }
#pragma unroll
  for (int m = 0; m < 4; ++m) {
    int row = m0 + 16 * m + ((lane >> 4) << 2);
    float dm[4];
#pragma unroll
    for (int j = 0; j < 4; ++j) dm[j] = dnorm[b * NDIM + row + j];
#pragma unroll
    for (int n = 0; n < 4; ++n) {
      int col = 64 * w + 16 * n + (lane & 15);
      bf16x4 pk;
#pragma unroll
      for (int j = 0; j < 4; ++j) pk[j] = f2bf(acc[m][n][j] * dm[j]);
      *(bf16x4*)(st + ((size_t)(b * FDIM + col)) * NDIM + row) = pk;
    }
  }
}

// ---- Kernel 4: out = d_n * (adj @ St^T) + bias ----
// 512 threads (8 waves, 2x4), BM=64, BN=256, BK=64, grid=256.
// XCD-aware mapping: batch = blockIdx.x & 7 -> all 32 blocks of a batch land
// on one XCD; that batch's 1 MB St stays resident in the local L2 (32x reuse).
__global__ __launch_bounds__(512) void k_main(const float* __restrict__ adj,
                                              const short* __restrict__ st,
                                              const float* __restrict__ dnorm,
                                              const float* __restrict__ bias,
                                              float* __restrict__ out) {
  __shared__ short Al[2][64 * 64];
  __shared__ short Bl[2][256 * 64];
  int t = threadIdx.x, lane = t & 63, w = t >> 6;
  int wm = w & 1, wn = w >> 1;
  int b = blockIdx.x & 7;              // batch <-> XCD
  int n0 = (blockIdx.x >> 3) * 64;     // M-tile within batch
  const float* ab = adj + ((size_t)b * NDIM + n0) * NDIM;
  const short* stb = st + (size_t)b * FDIM * NDIM;

  // A staging: row = t>>3 (0..63), 8-f32 chunk = t&7; swizzled LDS dest
  int arow = t >> 3, ac8 = t & 7;
  const float* asrc = ab + (size_t)arow * NDIM + ac8 * 8;
  int adst = arow * 64 + ((ac8 ^ (arow & 7)) * 8);
  // B staging source (pre-swizzled global chunk, linear LDS dest)
  int schk = ac8 ^ (arow & 7);
  const short* bsrc = stb + (size_t)arow * NDIM + 8 * schk;

  f32x4 acc[2][4];
#pragma unroll
  for (int m = 0; m < 2; ++m)
#pragma unroll
    for (int n = 0; n < 4; ++n) acc[m][n] = {0.f, 0.f, 0.f, 0.f};

  // prologue: stage K-tile 0 into buffer 0
  {
    f32x4 av0 = *(const f32x4*)(asrc);
    f32x4 av1 = *(const f32x4*)(asrc + 4);
#pragma unroll
    for (int i = 0; i < 4; ++i)
      gload_lds16(bsrc + (size_t)(i * 64) * NDIM, &Bl[0][(i * 512 + t) * 8]);
    bf16x8 ap;
#pragma unroll
    for (int j = 0; j < 4; ++j) { ap[j] = f2bf(av0[j]); ap[4 + j] = f2bf(av1[j]); }
    *(bf16x8*)&Al[0][adst] = ap;
  }
  __syncthreads();

  int lr = lane & 15, kg = lane >> 4, sw = lane & 7;

  for (int it = 0; it < 32; ++it) {
    int cur = it & 1, nxt = cur ^ 1;
    f32x4 av0, av1;
    if (it < 31) {
      int k0 = (it + 1) * 64;
      av0 = *(const f32x4*)(asrc + k0);
      av1 = *(const f32x4*)(asrc + k0 + 4);
#pragma unroll
      for (int i = 0; i < 4; ++i)
        gload_lds16(bsrc + (size_t)(i * 64) * NDIM + k0, &Bl[nxt][(i * 512 + t) * 8]);
    }
#pragma unroll
    for (int h = 0; h < 2; ++h) {
      int kc = ((h * 4 + kg) ^ sw) * 8;
      bf16x8 af[2], bfv[4];
#pragma unroll
      for (int mf = 0; mf < 2; ++mf)
        af[mf] = *(const bf16x8*)&Al[cur][(wm * 32 + mf * 16 + lr) * 64 + kc];
#pragma unroll
      for (int nf = 0; nf < 4; ++nf)
        bfv[nf] = *(const bf16x8*)&Bl[cur][(wn * 64 + nf * 16 + lr) * 64 + kc];
#pragma unroll
      for (int mf = 0; mf < 2; ++mf)
#pragma unroll
        for (int nf = 0; nf < 4; ++nf)
          acc[mf][nf] = __builtin_amdgcn_mfma_f32_16x16x32_bf16(af[mf], bfv[nf], acc[mf][nf], 0, 0, 0);
    }
    if (it < 31) {
      bf16x8 ap;
#pragma unroll
      for (int j = 0; j < 4; ++j) { ap[j] = f2bf(av0[j]); ap[4 + j] = f2bf(av1[j]); }
      *(bf16x8*)&Al[nxt][adst] = ap;
    }
    __syncthreads();
  }

  // epilogue: out[b][row][col] = d_n[row]*acc + bias[col]
#pragma unroll
  for (int mf = 0; mf < 2; ++mf) {
    int row = n0 + wm * 32 + mf * 16 + kg * 4;
    f32x4 dr = *(const f32x4*)&dnorm[b * NDIM + row];
#pragma unroll
    for (int nf = 0; nf < 4; ++nf) {
      int col = wn * 64 + nf * 16 + lr;
      float bv = bias[col];
      float* op = out + ((size_t)b * NDIM + row) * FDIM + col;
#pragma unroll
      for (int j = 0; j < 4; ++j) op[(size_t)j * FDIM] = dr[j] * acc[mf][nf][j] + bv;
    }
  }
}

extern "C" void kernel_launch(void* const* d_in, const int* in_sizes, int n_in,
                              void* d_out, int out_size, void* d_ws, size_t ws_size,
                              hipStream_t stream) {
  (void)in_sizes; (void)n_in; (void)out_size; (void)ws_size;
  const float* input = (const float*)d_in[0];
  const float* adj = (const float*)d_in[1];
  const float* weight = (const float*)d_in[2];
  const float* bias = (const float*)d_in[3];
  float* out = (float*)d_out;

  char* ws = (char*)d_ws;
  short* st = (short*)ws;                                       // 8 MB  (bf16 S^T)
  float* dnorm = (float*)(ws + 8ull * 1024 * 1024);             // 64 KB
  float* part = (float*)(ws + 8ull * 1024 * 1024 + 65536);      // 2 MB
  short* wt = (short*)(ws + 8ull * 1024 * 1024 + 65536 + 2ull * 1024 * 1024);  // 128 KB

  k_colsum<<<dim3(BATCH * CH * 2), dim3(256), 0, stream>>>(adj, part);
  k_small<<<dim3(80), dim3(256), 0, stream>>>(part, dnorm, weight, wt);
  k_support<<<dim3(BATCH * (NDIM / 64)), dim3(256), 0, stream>>>(input, wt, dnorm, st);
  k_main<<<dim3(BATCH * (NDIM / 64)), dim3(512), 0, stream>>>(adj, st, dnorm, bias, out);
}

// Round 6
// 79.922 us; speedup vs baseline: 1.1414x; 1.1414x over previous
//
#include <hip/hip_runtime.h>

#define BATCH 8
#define NDIM 2048
#define FDIM 256
#define CH 32   // row-chunks for column-sum partials (64 rows each)

typedef float f32x4 __attribute__((ext_vector_type(4)));
typedef short bf16x8 __attribute__((ext_vector_type(8)));
typedef short bf16x4 __attribute__((ext_vector_type(4)));

__device__ __forceinline__ short f2bf(float f) {
  union { float f; unsigned u; } v{f};
  return (short)((v.u + 0x7FFFu + ((v.u >> 16) & 1u)) >> 16);  // RNE
}

__device__ __forceinline__ void gload_lds16(const void* g, void* l) {
  __builtin_amdgcn_global_load_lds(
      (const __attribute__((address_space(1))) void*)g,
      (__attribute__((address_space(3))) void*)l, 16, 0, 0);
}

// ---- Kernel 1: partial column sums of adj + bf16 re-emit (abf) ----
__global__ __launch_bounds__(256) void k_colsum(const float* __restrict__ adj,
                                                float* __restrict__ part,
                                                short* __restrict__ abf) {
  int bid = blockIdx.x;
  int cb = bid & 1;
  int ch = (bid >> 1) & (CH - 1);
  int b = bid >> 6;
  int col = cb * 1024 + threadIdx.x * 4;
  size_t base = (size_t)b * NDIM * NDIM + (size_t)(ch * 64) * NDIM + col;
  const float* p = adj + base;
  short* q = abf + base;
  f32x4 acc = {0.f, 0.f, 0.f, 0.f};
#pragma unroll 8
  for (int i = 0; i < 64; ++i) {
    f32x4 v = *(const f32x4*)(p + (size_t)i * NDIM);
    acc += v;
    bf16x4 pk;
#pragma unroll
    for (int j = 0; j < 4; ++j) pk[j] = f2bf(v[j]);
    *(bf16x4*)(q + (size_t)i * NDIM) = pk;
  }
  *(f32x4*)(part + (size_t)(b * CH + ch) * NDIM + col) = acc;
}

// ---- Kernel 2 (merged): blocks 0..63 -> d = rsqrt(colsum); 64..79 -> Wt ----
__global__ __launch_bounds__(256) void k_small(const float* __restrict__ part,
                                               float* __restrict__ dnorm,
                                               const float* __restrict__ w,
                                               short* __restrict__ wt) {
  int t = threadIdx.x;
  if (blockIdx.x < 64) {
    int idx = blockIdx.x * 256 + t;  // b*NDIM + j
    int b = idx >> 11, j = idx & (NDIM - 1);
    float s = 0.f;
#pragma unroll
    for (int c = 0; c < CH; ++c) s += part[(size_t)(b * CH + c) * NDIM + j];
    dnorm[idx] = rsqrtf(s);
  } else {
    __shared__ float tile[64][65];
    int bb = blockIdx.x - 64;
    int bx = bb & 3, by = bb >> 2;
    int f0 = by * 64, o0 = bx * 64;
    int c4 = 4 * (t & 15);
#pragma unroll
    for (int q = 0; q < 4; ++q) {
      int r = (t >> 4) + 16 * q;
      f32x4 v = *(const f32x4*)(w + (size_t)(f0 + r) * FDIM + o0 + c4);
#pragma unroll
      for (int i = 0; i < 4; ++i) tile[r][c4 + i] = v[i];
    }
    __syncthreads();
#pragma unroll
    for (int q = 0; q < 4; ++q) {
      int r = (t >> 4) + 16 * q;
      bf16x4 pk;
#pragma unroll
      for (int i = 0; i < 4; ++i) pk[i] = f2bf(tile[c4 + i][r]);
      *(bf16x4*)(wt + (size_t)(o0 + r) * FDIM + f0 + c4) = pk;
    }
  }
}

// ---- Kernel 3: St[b][o][m] = bf16(d[b][m] * (X @ W)[m][o]) ----
__global__ __launch_bounds__(256) void k_support(const float* __restrict__ in,
                                                 const short* __restrict__ wt,
                                                 const float* __restrict__ dnorm,
                                                 short* __restrict__ st) {
  __shared__ short Al[64 * 32];
  __shared__ short Bl[256 * 32];
  int t = threadIdx.x, lane = t & 63, w = t >> 6;
  int b = blockIdx.x >> 5;
  int m0 = (blockIdx.x & 31) * 64;
  const float* inb = in + ((size_t)b * NDIM + m0) * FDIM;

  f32x4 acc[4][4];
#pragma unroll
  for (int m = 0; m < 4; ++m)
#pragma unroll
    for (int n = 0; n < 4; ++n) acc[m][n] = {0.f, 0.f, 0.f, 0.f};

  int ar = t >> 2, ac = t & 3;
  for (int it = 0; it < 8; ++it) {
    int k0 = it * 32;
    {
      f32x4 v0 = *(const f32x4*)(inb + (size_t)ar * FDIM + k0 + 8 * ac);
      f32x4 v1 = *(const f32x4*)(inb + (size_t)ar * FDIM + k0 + 8 * ac + 4);
      bf16x8 p;
#pragma unroll
      for (int i = 0; i < 4; ++i) { p[i] = f2bf(v0[i]); p[4 + i] = f2bf(v1[i]); }
      *(bf16x8*)&Al[ar * 32 + 8 * ac] = p;
    }
#pragma unroll
    for (int i = 0; i < 4; ++i) {
      int ss = i * 256 + t;
      int o = ss >> 2, c = ss & 3;
      gload_lds16(wt + (size_t)o * FDIM + k0 + 8 * c, &Bl[ss * 8]);
    }
    __syncthreads();
    bf16x8 af[4], bf[4];
#pragma unroll
    for (int m = 0; m < 4; ++m)
      af[m] = *(const bf16x8*)&Al[(16 * m + (lane & 15)) * 32 + (lane >> 4) * 8];
#pragma unroll
    for (int n = 0; n < 4; ++n)
      bf[n] = *(const bf16x8*)&Bl[(64 * w + 16 * n + (lane & 15)) * 32 + (lane >> 4) * 8];
#pragma unroll
    for (int m = 0; m < 4; ++m)
#pragma unroll
      for (int n = 0; n < 4; ++n)
        acc[m][n] = __builtin_amdgcn_mfma_f32_16x16x32_bf16(af[m], bf[n], acc[m][n], 0, 0, 0);
    __syncthreads();
  }
#pragma unroll
  for (int m = 0; m < 4; ++m) {
    int row = m0 + 16 * m + ((lane >> 4) << 2);
    float dm[4];
#pragma unroll
    for (int j = 0; j < 4; ++j) dm[j] = dnorm[b * NDIM + row + j];
#pragma unroll
    for (int n = 0; n < 4; ++n) {
      int col = 64 * w + 16 * n + (lane & 15);
      bf16x4 pk;
#pragma unroll
      for (int j = 0; j < 4; ++j) pk[j] = f2bf(acc[m][n][j] * dm[j]);
      *(bf16x4*)(st + ((size_t)(b * FDIM + col)) * NDIM + row) = pk;
    }
  }
}

// ---- Kernel 4: out = d_n * (abf @ St^T) + bias ----
// 512 threads (8 waves, 2x4), BM=64, BN=256, BK=64, grid=256.
// Counted-vmcnt depth-2 pipeline, triple-buffered, all global_load_lds.
// RACE FIX vs R5: vmcnt(10) -> s_barrier BEFORE ds_read (tile globally
// complete), second s_barrier after lgkmcnt(0) (reads done before overwrite).
__global__ __launch_bounds__(512) void k_main(const short* __restrict__ abf,
                                              const short* __restrict__ st,
                                              const float* __restrict__ dnorm,
                                              const float* __restrict__ bias,
                                              float* __restrict__ out) {
  __shared__ short Al[3][64 * 64];    // 3 x 8 KB
  __shared__ short Bl[3][256 * 64];   // 3 x 32 KB
  int t = threadIdx.x, lane = t & 63, w = t >> 6;
  int wm = w & 1, wn = w >> 1;
  int b = blockIdx.x & 7;              // batch <-> XCD (round-robin dispatch)
  int n0 = (blockIdx.x >> 3) * 64;     // M-tile within batch
  const short* ab = abf + ((size_t)b * NDIM + n0) * NDIM;
  const short* stb = st + (size_t)b * FDIM * NDIM;

  // staging: row = t>>3 (0..63), 16B chunk = t&7, source pre-XOR-swizzled
  int arow = t >> 3;
  int schk = (t & 7) ^ (arow & 7);
  const short* asrc = ab + (size_t)arow * NDIM + 8 * schk;
  const short* bsrc = stb + (size_t)arow * NDIM + 8 * schk;

  f32x4 acc[2][4];
#pragma unroll
  for (int m = 0; m < 2; ++m)
#pragma unroll
    for (int n = 0; n < 4; ++n) acc[m][n] = {0.f, 0.f, 0.f, 0.f};

  int lr = lane & 15, kg = lane >> 4, sw = lane & 7;

  // S(k): issue 1 A-gll + 4 B-gll for K-tile k into buffer bp
  auto stage = [&](int k, int bp) {
    int kc = k > 31 ? 31 : k;
    size_t ko = (size_t)kc * 64;
    gload_lds16(asrc + ko, &Al[bp][t * 8]);
#pragma unroll
    for (int i = 0; i < 4; ++i)
      gload_lds16(bsrc + (size_t)(i * 64) * NDIM + ko, &Bl[bp][(i * 512 + t) * 8]);
  };

  auto body = [&](int it, int bc, int bp) {
    stage(it + 2, bp);
    // drain own S(it) loads, then rendezvous: buffer bc globally complete
    asm volatile("s_waitcnt vmcnt(10)" ::: "memory");
    __builtin_amdgcn_s_barrier();
    asm volatile("" ::: "memory");
    __builtin_amdgcn_sched_barrier(0);
#pragma unroll
    for (int h = 0; h < 2; ++h) {
      int kc = ((h * 4 + kg) ^ sw) * 8;
      bf16x8 af0 = *(const bf16x8*)&Al[bc][(wm * 32 + lr) * 64 + kc];
      bf16x8 af1 = *(const bf16x8*)&Al[bc][(wm * 32 + 16 + lr) * 64 + kc];
      bf16x8 bv0 = *(const bf16x8*)&Bl[bc][(wn * 64 + lr) * 64 + kc];
      bf16x8 bv1 = *(const bf16x8*)&Bl[bc][(wn * 64 + 16 + lr) * 64 + kc];
      bf16x8 bv2 = *(const bf16x8*)&Bl[bc][(wn * 64 + 32 + lr) * 64 + kc];
      bf16x8 bv3 = *(const bf16x8*)&Bl[bc][(wn * 64 + 48 + lr) * 64 + kc];
      acc[0][0] = __builtin_amdgcn_mfma_f32_16x16x32_bf16(af0, bv0, acc[0][0], 0, 0, 0);
      acc[0][1] = __builtin_amdgcn_mfma_f32_16x16x32_bf16(af0, bv1, acc[0][1], 0, 0, 0);
      acc[0][2] = __builtin_amdgcn_mfma_f32_16x16x32_bf16(af0, bv2, acc[0][2], 0, 0, 0);
      acc[0][3] = __builtin_amdgcn_mfma_f32_16x16x32_bf16(af0, bv3, acc[0][3], 0, 0, 0);
      acc[1][0] = __builtin_amdgcn_mfma_f32_16x16x32_bf16(af1, bv0, acc[1][0], 0, 0, 0);
      acc[1][1] = __builtin_amdgcn_mfma_f32_16x16x32_bf16(af1, bv1, acc[1][1], 0, 0, 0);
      acc[1][2] = __builtin_amdgcn_mfma_f32_16x16x32_bf16(af1, bv2, acc[1][2], 0, 0, 0);
      acc[1][3] = __builtin_amdgcn_mfma_f32_16x16x32_bf16(af1, bv3, acc[1][3], 0, 0, 0);
    }
    // reads of buffer bc done -> next body's stage may overwrite bc
    asm volatile("s_waitcnt lgkmcnt(0)" ::: "memory");
    __builtin_amdgcn_s_barrier();
    asm volatile("" ::: "memory");
  };

  // prologue: S(0)->buf0, S(1)->buf1 (10 in flight)
  stage(0, 0);
  stage(1, 1);

  for (int itb = 0; itb < 30; itb += 3) {
    body(itb + 0, 0, 2);
    body(itb + 1, 1, 0);
    body(itb + 2, 2, 1);
  }
  body(30, 0, 2);
  body(31, 1, 0);

  // epilogue: out[b][row][col] = d_n[row]*acc + bias[col]
#pragma unroll
  for (int mf = 0; mf < 2; ++mf) {
    int row = n0 + wm * 32 + mf * 16 + kg * 4;
    f32x4 dr = *(const f32x4*)&dnorm[b * NDIM + row];
#pragma unroll
    for (int nf = 0; nf < 4; ++nf) {
      int col = wn * 64 + nf * 16 + lr;
      float bv = bias[col];
      float* op = out + ((size_t)b * NDIM + row) * FDIM + col;
#pragma unroll
      for (int j = 0; j < 4; ++j) op[(size_t)j * FDIM] = dr[j] * acc[mf][nf][j] + bv;
    }
  }
}

extern "C" void kernel_launch(void* const* d_in, const int* in_sizes, int n_in,
                              void* d_out, int out_size, void* d_ws, size_t ws_size,
                              hipStream_t stream) {
  (void)in_sizes; (void)n_in; (void)out_size; (void)ws_size;
  const float* input = (const float*)d_in[0];
  const float* adj = (const float*)d_in[1];
  const float* weight = (const float*)d_in[2];
  const float* bias = (const float*)d_in[3];
  float* out = (float*)d_out;

  char* ws = (char*)d_ws;
  short* st = (short*)ws;                                       // 8 MB  (bf16 S^T)
  float* dnorm = (float*)(ws + 8ull * 1024 * 1024);             // 64 KB
  float* part = (float*)(ws + 8ull * 1024 * 1024 + 65536);      // 2 MB
  short* wt = (short*)(ws + 8ull * 1024 * 1024 + 65536 + 2ull * 1024 * 1024);  // 128 KB
  short* abf = (short*)(ws + 16ull * 1024 * 1024);              // 64 MB (bf16 adj)

  k_colsum<<<dim3(BATCH * CH * 2), dim3(256), 0, stream>>>(adj, part, abf);
  k_small<<<dim3(80), dim3(256), 0, stream>>>(part, dnorm, weight, wt);
  k_support<<<dim3(BATCH * (NDIM / 64)), dim3(256), 0, stream>>>(input, wt, dnorm, st);
  k_main<<<dim3(BATCH * (NDIM / 64)), dim3(512), 0, stream>>>(abf, st, dnorm, bias, out);
}